// Round 2
// baseline (654.260 us; speedup 1.0000x reference)
//
#include <hip/hip_runtime.h>

#define Nn 2048
#define Bb 16
#define Dd 8
#define BN (Bb * Nn)       // 32768
#define NN ((size_t)Nn * Nn)
#define EC 4               // e-rows per block (was 16): 1024 blocks -> 16 waves/CU
#define ECH (Nn / EC)      // 512 e-chunks

typedef float v4f __attribute__((ext_vector_type(4)));

// Prep: zero the output accumulator and build xw[e][b][d] = Xd*(Wshort+1).
__global__ void prep_kernel(const float* __restrict__ Xd,
                            const float* __restrict__ Wshort,
                            float* __restrict__ xw,
                            float* __restrict__ out) {
    int t = blockIdx.x * blockDim.x + threadIdx.x;   // t in [0, BN)
    if (t >= BN) return;
    out[t] = 0.0f;                                   // out is exactly B*N floats
    int b = t >> 11;            // t / N
    int e = t & (Nn - 1);       // t % N
    float v[Dd];
#pragma unroll
    for (int d = 0; d < Dd; ++d) {
        int idx = d * BN + b * Nn + e;               // coalesced over e
        v[d] = Xd[idx] * (Wshort[idx] + 1.0f);
    }
    v4f* dst = (v4f*)(xw + (size_t)e * (Bb * Dd) + b * Dd);  // 32B aligned
    dst[0] = (v4f){v[0], v[1], v[2], v[3]};
    dst[1] = (v4f){v[4], v[5], v[6], v[7]};
}

__global__ __launch_bounds__(256) void main_kernel(
        const float* __restrict__ W,
        const float* __restrict__ Wlong,
        const float* __restrict__ delaymap,
        const float* __restrict__ frac,
        const float* __restrict__ signs_pre,
        const float* __restrict__ xw,
        float* __restrict__ out) {
    const int o = (blockIdx.x * 256 + threadIdx.x) * 4;   // 4 consecutive o's
    const int e0 = blockIdx.y * EC;

    v4f acc[Bb];
#pragma unroll
    for (int b = 0; b < Bb; ++b) acc[b] = (v4f)0.0f;

#pragma unroll
    for (int ei = 0; ei < EC; ++ei) {
        const int e = e0 + ei;
        const float sp = signs_pre[e];
        const float sgn = (sp > 0.0f) ? 1.0f : ((sp < 0.0f) ? -1.0f : 0.0f);

        const size_t eo = (size_t)e * Nn + o;
        const v4f w  = *(const v4f*)(W + eo);
        const v4f fr = *(const v4f*)(frac + eo);

        v4f dm[Dd];
#pragma unroll
        for (int d = 0; d < Dd; ++d)
            dm[d] = *(const v4f*)(delaymap + (size_t)d * NN + eo);

        v4f sg, base;
#pragma unroll
        for (int c = 0; c < 4; ++c) {
            sg[c]   = (w[c] > 0.0f) ? sgn : 0.0f;
            base[c] = w[c] * (1.0f - fr[c]);
        }

        const float* xwe = xw + (size_t)e * (Bb * Dd);   // wave-uniform -> s_load

#pragma unroll
        for (int b = 0; b < Bb; ++b) {
            const v4f wl = *(const v4f*)(Wlong + (size_t)b * NN + eo);
            v4f inner = (v4f)0.0f;
#pragma unroll
            for (int d = 0; d < Dd; ++d)
                inner += dm[d] * xwe[b * Dd + d];
            const v4f weff = sg * (base + wl * fr);
            acc[b] += weff * inner;
        }
    }

#pragma unroll
    for (int b = 0; b < Bb; ++b) {
        float* op = out + b * Nn + o;
        atomicAdd(op + 0, acc[b][0]);
        atomicAdd(op + 1, acc[b][1]);
        atomicAdd(op + 2, acc[b][2]);
        atomicAdd(op + 3, acc[b][3]);
    }
}

extern "C" void kernel_launch(void* const* d_in, const int* in_sizes, int n_in,
                              void* d_out, int out_size, void* d_ws, size_t ws_size,
                              hipStream_t stream) {
    const float* W         = (const float*)d_in[0];
    const float* Wlong     = (const float*)d_in[1];
    const float* Wshort    = (const float*)d_in[2];
    const float* Xd        = (const float*)d_in[3];
    const float* delaymap  = (const float*)d_in[4];
    const float* frac      = (const float*)d_in[5];
    const float* signs_pre = (const float*)d_in[6];
    float* out = (float*)d_out;
    float* xw  = (float*)d_ws;   // needs B*N*D*4 = 1 MB

    prep_kernel<<<BN / 256, 256, 0, stream>>>(Xd, Wshort, xw, out);

    dim3 grid(Nn / (256 * 4), ECH);   // 2 x 512 = 1024 blocks
    main_kernel<<<grid, 256, 0, stream>>>(W, Wlong, delaymap, frac, signs_pre,
                                          xw, out);
}

// Round 3
// 501.348 us; speedup vs baseline: 1.3050x; 1.3050x over previous
//
#include <hip/hip_runtime.h>

#define Nn 2048
#define Bb 16
#define Dd 8
#define BN (Bb * Nn)       // 32768
#define NN ((size_t)Nn * Nn)
#define EC 4               // e-rows per block: 1024 blocks
#define ECH (Nn / EC)      // 512 e-chunks

#define XW_BYTES   ((size_t)Nn * Bb * Dd * 4)          // 1 MB
#define PART_BYTES ((size_t)ECH * BN * 4)              // 67 MB
#define RCG 8                                          // reduce chunk-groups

typedef float v4f __attribute__((ext_vector_type(4)));

// Prep: zero the output accumulator and build xw[e][b][d] = Xd*(Wshort+1).
__global__ void prep_kernel(const float* __restrict__ Xd,
                            const float* __restrict__ Wshort,
                            float* __restrict__ xw,
                            float* __restrict__ out) {
    int t = blockIdx.x * blockDim.x + threadIdx.x;   // t in [0, BN)
    if (t >= BN) return;
    out[t] = 0.0f;
    int b = t >> 11;            // t / N
    int e = t & (Nn - 1);       // t % N
    float v[Dd];
#pragma unroll
    for (int d = 0; d < Dd; ++d) {
        int idx = d * BN + b * Nn + e;               // coalesced over e
        v[d] = Xd[idx] * (Wshort[idx] + 1.0f);
    }
    v4f* dst = (v4f*)(xw + (size_t)e * (Bb * Dd) + b * Dd);  // 32B aligned
    dst[0] = (v4f){v[0], v[1], v[2], v[3]};
    dst[1] = (v4f){v[4], v[5], v[6], v[7]};
}

template <bool USE_PART>
__global__ __launch_bounds__(256) void main_kernel(
        const float* __restrict__ W,
        const float* __restrict__ Wlong,
        const float* __restrict__ delaymap,
        const float* __restrict__ frac,
        const float* __restrict__ signs_pre,
        const float* __restrict__ xw,
        float* __restrict__ partial,
        float* __restrict__ out) {
    const int o = (blockIdx.x * 256 + threadIdx.x) * 4;   // 4 consecutive o's
    const int chunk = blockIdx.y;
    const int e0 = chunk * EC;

    v4f acc[Bb];
#pragma unroll
    for (int b = 0; b < Bb; ++b) acc[b] = (v4f)0.0f;

#pragma unroll
    for (int ei = 0; ei < EC; ++ei) {
        const int e = e0 + ei;
        const float sp = signs_pre[e];
        const float sgn = (sp > 0.0f) ? 1.0f : ((sp < 0.0f) ? -1.0f : 0.0f);

        const size_t eo = (size_t)e * Nn + o;
        const v4f w  = *(const v4f*)(W + eo);
        const v4f fr = *(const v4f*)(frac + eo);

        v4f dm[Dd];
#pragma unroll
        for (int d = 0; d < Dd; ++d)
            dm[d] = *(const v4f*)(delaymap + (size_t)d * NN + eo);

        v4f sg, base;
#pragma unroll
        for (int c = 0; c < 4; ++c) {
            sg[c]   = (w[c] > 0.0f) ? sgn : 0.0f;
            base[c] = w[c] * (1.0f - fr[c]);
        }

        const float* xwe = xw + (size_t)e * (Bb * Dd);   // wave-uniform -> s_load

#pragma unroll
        for (int b = 0; b < Bb; ++b) {
            const v4f wl = *(const v4f*)(Wlong + (size_t)b * NN + eo);
            v4f inner = (v4f)0.0f;
#pragma unroll
            for (int d = 0; d < Dd; ++d)
                inner += dm[d] * xwe[b * Dd + d];
            const v4f weff = sg * (base + wl * fr);
            acc[b] += weff * inner;
        }
    }

    if (USE_PART) {
        float* pbase = partial + (size_t)chunk * BN + o;
#pragma unroll
        for (int b = 0; b < Bb; ++b)
            *(v4f*)(pbase + b * Nn) = acc[b];
    } else {
#pragma unroll
        for (int b = 0; b < Bb; ++b) {
            float* op = out + b * Nn + o;
            atomicAdd(op + 0, acc[b][0]);
            atomicAdd(op + 1, acc[b][1]);
            atomicAdd(op + 2, acc[b][2]);
            atomicAdd(op + 3, acc[b][3]);
        }
    }
}

// Reduce: out[t] += sum over a 64-chunk group of partial[c][t].
__global__ __launch_bounds__(256) void reduce_kernel(
        const float* __restrict__ partial, float* __restrict__ out) {
    const int t = blockIdx.x * 256 + threadIdx.x;   // [0, BN)
    const int cg = blockIdx.y;                      // [0, RCG)
    const int c0 = cg * (ECH / RCG);
    float s0 = 0.f, s1 = 0.f, s2 = 0.f, s3 = 0.f;
#pragma unroll 4
    for (int c = c0; c < c0 + (ECH / RCG); c += 4) {
        s0 += partial[(size_t)(c + 0) * BN + t];
        s1 += partial[(size_t)(c + 1) * BN + t];
        s2 += partial[(size_t)(c + 2) * BN + t];
        s3 += partial[(size_t)(c + 3) * BN + t];
    }
    atomicAdd(out + t, (s0 + s1) + (s2 + s3));
}

extern "C" void kernel_launch(void* const* d_in, const int* in_sizes, int n_in,
                              void* d_out, int out_size, void* d_ws, size_t ws_size,
                              hipStream_t stream) {
    const float* W         = (const float*)d_in[0];
    const float* Wlong     = (const float*)d_in[1];
    const float* Wshort    = (const float*)d_in[2];
    const float* Xd        = (const float*)d_in[3];
    const float* delaymap  = (const float*)d_in[4];
    const float* frac      = (const float*)d_in[5];
    const float* signs_pre = (const float*)d_in[6];
    float* out = (float*)d_out;
    float* xw  = (float*)d_ws;                       // 1 MB
    float* partial = (float*)((char*)d_ws + XW_BYTES);

    prep_kernel<<<BN / 256, 256, 0, stream>>>(Xd, Wshort, xw, out);

    dim3 grid(Nn / (256 * 4), ECH);   // 2 x 512 = 1024 blocks
    if (ws_size >= XW_BYTES + PART_BYTES) {
        main_kernel<true><<<grid, 256, 0, stream>>>(W, Wlong, delaymap, frac,
                                                    signs_pre, xw, partial, out);
        dim3 rgrid(BN / 256, RCG);    // 128 x 8 = 1024 blocks
        reduce_kernel<<<rgrid, 256, 0, stream>>>(partial, out);
    } else {
        main_kernel<false><<<grid, 256, 0, stream>>>(W, Wlong, delaymap, frac,
                                                     signs_pre, xw, partial, out);
    }
}